// Round 3
// baseline (413.261 us; speedup 1.0000x reference)
//
#include <hip/hip_runtime.h>

typedef __bf16 bf16_t;
typedef __bf16 bf16x4 __attribute__((ext_vector_type(4)));
typedef __bf16 bf16x8 __attribute__((ext_vector_type(8)));
typedef float f32x4 __attribute__((ext_vector_type(4)));

#define AS1 __attribute__((address_space(1)))
#define AS3 __attribute__((address_space(3)))

// async global->LDS, 16B per lane; LDS dest = wave-uniform base + lane*16
__device__ __forceinline__ void gll16(const void* g, void* l) {
  __builtin_amdgcn_global_load_lds((AS1 void*)g, (AS3 void*)l, 16, 0, 0);
}

// ---------------------------------------------------------------------------
// GEMM core: C(32768x512) = act(A(32768x512,bf16) @ BT^T + bias)
// BT is W^T (512x512, bf16) so B-fragments read contiguous k.
// ACT: 0 = identity->bf16, 1 = per-64-group softmax->bf16, 2 = identity->fp32
// TRANS: store as T[(b*8+h)*64 + d][m] (head-transposed, for kv GEMM operands)
// Tiles: 128x128, BK=64, 4 waves in 2x2 grid, each wave 64x64 via 4x4 frags.
// ---------------------------------------------------------------------------
template <int ACT, bool TRANS>
__device__ __forceinline__ void gemm_core(const bf16_t* __restrict__ A,
                                          const bf16_t* __restrict__ BT,
                                          const float* __restrict__ bias,
                                          void* __restrict__ Cout,
                                          int rowbase, int colbase) {
  __shared__ __align__(16) bf16_t As[128 * 64];
  __shared__ __align__(16) bf16_t Bs[128 * 64];
  const int tid = threadIdx.x;
  const int lane = tid & 63, wid = tid >> 6;
  const int wr = wid >> 1, wc = wid & 1;

  f32x4 zero = {0.f, 0.f, 0.f, 0.f};
  f32x4 acc[4][4];
#pragma unroll
  for (int i = 0; i < 4; ++i)
#pragma unroll
    for (int j = 0; j < 4; ++j) acc[i][j] = zero;

  const int srow = wid * 8 + (lane >> 3);   // + i*32
  const int scol = (lane & 7) * 8;
  const size_t abase = (size_t)(rowbase + srow) * 512 + scol;
  const size_t bbase = (size_t)(colbase + srow) * 512 + scol;
  bf16_t* lA = As + wid * 512;
  bf16_t* lB = Bs + wid * 512;

  for (int k0 = 0; k0 < 512; k0 += 64) {
#pragma unroll
    for (int i = 0; i < 4; ++i) {
      gll16(A + abase + (size_t)i * (32 * 512) + k0, lA + i * 2048);
      gll16(BT + bbase + (size_t)i * (32 * 512) + k0, lB + i * 2048);
    }
    __syncthreads();
#pragma unroll
    for (int kk = 0; kk < 64; kk += 32) {
      bf16x8 af[4], bfr[4];
#pragma unroll
      for (int ri = 0; ri < 4; ++ri)
        af[ri] = *(const bf16x8*)&As[(wr * 64 + ri * 16 + (lane & 15)) * 64 + kk + (lane >> 4) * 8];
#pragma unroll
      for (int ci = 0; ci < 4; ++ci)
        bfr[ci] = *(const bf16x8*)&Bs[(wc * 64 + ci * 16 + (lane & 15)) * 64 + kk + (lane >> 4) * 8];
#pragma unroll
      for (int ri = 0; ri < 4; ++ri)
#pragma unroll
        for (int ci = 0; ci < 4; ++ci)
          acc[ri][ci] = __builtin_amdgcn_mfma_f32_16x16x32_bf16(af[ri], bfr[ci], acc[ri][ci], 0, 0, 0);
    }
    __syncthreads();
  }

  // epilogue: bias (+ softmax per 64-col head group)
  float bb[4];
#pragma unroll
  for (int ci = 0; ci < 4; ++ci) bb[ci] = bias[colbase + wc * 64 + ci * 16 + (lane & 15)];
#pragma unroll
  for (int ri = 0; ri < 4; ++ri)
#pragma unroll
    for (int ci = 0; ci < 4; ++ci)
#pragma unroll
      for (int r = 0; r < 4; ++r) acc[ri][ci][r] += bb[ci];

  if (ACT == 1) {
    // wave's 64 cols == one head group (col tile offsets are multiples of 64)
#pragma unroll
    for (int ri = 0; ri < 4; ++ri) {
#pragma unroll
      for (int r = 0; r < 4; ++r) {
        float m = fmaxf(fmaxf(acc[ri][0][r], acc[ri][1][r]), fmaxf(acc[ri][2][r], acc[ri][3][r]));
        m = fmaxf(m, __shfl_xor(m, 1));
        m = fmaxf(m, __shfl_xor(m, 2));
        m = fmaxf(m, __shfl_xor(m, 4));
        m = fmaxf(m, __shfl_xor(m, 8));
        float s = 0.f;
#pragma unroll
        for (int ci = 0; ci < 4; ++ci) {
          float p = __expf(acc[ri][ci][r] - m);
          acc[ri][ci][r] = p;
          s += p;
        }
        s += __shfl_xor(s, 1);
        s += __shfl_xor(s, 2);
        s += __shfl_xor(s, 4);
        s += __shfl_xor(s, 8);
        float rcp = 1.0f / s;
#pragma unroll
        for (int ci = 0; ci < 4; ++ci) acc[ri][ci][r] *= rcp;
      }
    }
  }

  const int lr = (lane >> 4) * 4, lc = lane & 15;
  if (TRANS) {
    // packed 8B stores: the 4 r-values are 4 consecutive m in T layout
#pragma unroll
    for (int ri = 0; ri < 4; ++ri)
#pragma unroll
      for (int ci = 0; ci < 4; ++ci) {
        bf16x4 pk;
#pragma unroll
        for (int r = 0; r < 4; ++r) pk[r] = (bf16_t)acc[ri][ci][r];
        int gm0 = rowbase + wr * 64 + ri * 16 + lr;
        int c = colbase + wc * 64 + ci * 16 + lc;
        size_t idx = ((size_t)((gm0 >> 13) * 8 + (c >> 6)) * 64 + (c & 63)) * 8192 + (gm0 & 8191);
        *(bf16x4*)&((bf16_t*)Cout)[idx] = pk;
      }
  } else {
#pragma unroll
    for (int ri = 0; ri < 4; ++ri)
#pragma unroll
      for (int ci = 0; ci < 4; ++ci)
#pragma unroll
        for (int r = 0; r < 4; ++r) {
          int gm = rowbase + wr * 64 + ri * 16 + lr + r;
          int c = colbase + wc * 64 + ci * 16 + lc;
          size_t idx = (size_t)gm * 512 + c;
          if (ACT == 2)
            ((float*)Cout)[idx] = acc[ri][ci][r];
          else
            ((bf16_t*)Cout)[idx] = (bf16_t)acc[ri][ci][r];
        }
  }
}

// fused Q/K/V projections: blockIdx.z selects which GEMM
__launch_bounds__(256, 2)
__global__ void qkv_k(const bf16_t* __restrict__ xbf, const bf16_t* __restrict__ ybf,
                      const bf16_t* __restrict__ WqT, const bf16_t* __restrict__ WkT,
                      const bf16_t* __restrict__ WvT,
                      const float* __restrict__ bq, const float* __restrict__ bk,
                      const float* __restrict__ bv,
                      bf16_t* __restrict__ Qb, bf16_t* __restrict__ Kt,
                      bf16_t* __restrict__ Vt) {
  const int rowbase = blockIdx.x * 128, colbase = blockIdx.y * 128;
  if (blockIdx.z == 0)
    gemm_core<1, false>(xbf, WqT, bq, Qb, rowbase, colbase);
  else if (blockIdx.z == 1)
    gemm_core<1, true>(ybf, WkT, bk, Kt, rowbase, colbase);
  else
    gemm_core<0, true>(ybf, WvT, bv, Vt, rowbase, colbase);
}

// output projection -> fp32
__launch_bounds__(256, 2)
__global__ void pgemm_k(const bf16_t* __restrict__ A, const bf16_t* __restrict__ BT,
                        const float* __restrict__ bias, float* __restrict__ Cout) {
  gemm_core<2, false>(A, BT, bias, Cout, blockIdx.x * 128, blockIdx.y * 128);
}

// ---------------------------------------------------------------------------
// kv partials: kvp[sp][bh][d][e] = sum_{m in split sp} Kt[bh][d][m]*Vt[bh][e][m]
// ksp[sp][bh][d] likewise vs all-ones. No atomics; build_kvB reduces.
// ---------------------------------------------------------------------------
__launch_bounds__(256, 2)
__global__ void kv2_k(const bf16_t* __restrict__ Kt, const bf16_t* __restrict__ Vt,
                      float* __restrict__ kvp, float* __restrict__ ksp) {
  __shared__ __align__(16) bf16_t Ks[64 * 64];
  __shared__ __align__(16) bf16_t Vs[64 * 64];
  const int bh = blockIdx.x >> 4, sp = blockIdx.x & 15;
  const int tid = threadIdx.x, lane = tid & 63, wid = tid >> 6;
  const size_t base = (size_t)bh * 64 * 8192;
  const int m0 = sp * 512;
  const int srow = wid * 8 + (lane >> 3);  // + i*32
  const int scol = (lane & 7) * 8;

  f32x4 zero = {0.f, 0.f, 0.f, 0.f};
  f32x4 acc[4], accs[4];
#pragma unroll
  for (int i = 0; i < 4; ++i) { acc[i] = zero; accs[i] = zero; }
  bf16x8 ones;
#pragma unroll
  for (int j = 0; j < 8; ++j) ones[j] = (bf16_t)1.0f;

  for (int c = 0; c < 8; ++c) {
    const int mc = m0 + c * 64;
#pragma unroll
    for (int i = 0; i < 2; ++i) {
      size_t g = base + (size_t)(srow + i * 32) * 8192 + mc + scol;
      gll16(Kt + g, Ks + wid * 512 + i * 2048);
      gll16(Vt + g, Vs + wid * 512 + i * 2048);
    }
    __syncthreads();
#pragma unroll
    for (int kk = 0; kk < 64; kk += 32) {
      bf16x8 af[4];
#pragma unroll
      for (int ri = 0; ri < 4; ++ri)
        af[ri] = *(const bf16x8*)&Ks[(ri * 16 + (lane & 15)) * 64 + kk + (lane >> 4) * 8];
      bf16x8 bfr = *(const bf16x8*)&Vs[(wid * 16 + (lane & 15)) * 64 + kk + (lane >> 4) * 8];
#pragma unroll
      for (int ri = 0; ri < 4; ++ri)
        acc[ri] = __builtin_amdgcn_mfma_f32_16x16x32_bf16(af[ri], bfr, acc[ri], 0, 0, 0);
      if (wid == 0) {
#pragma unroll
        for (int ri = 0; ri < 4; ++ri)
          accs[ri] = __builtin_amdgcn_mfma_f32_16x16x32_bf16(af[ri], ones, accs[ri], 0, 0, 0);
      }
    }
    __syncthreads();
  }

  const int lr = (lane >> 4) * 4, lc = lane & 15;
  float* o = kvp + ((size_t)sp * 32 + bh) * 4096;
#pragma unroll
  for (int ri = 0; ri < 4; ++ri)
#pragma unroll
    for (int r = 0; r < 4; ++r)
      o[(ri * 16 + lr + r) * 64 + wid * 16 + lc] = acc[ri][r];
  if (wid == 0 && lc == 0) {
    float* os = ksp + ((size_t)sp * 32 + bh) * 64;
#pragma unroll
    for (int ri = 0; ri < 4; ++ri)
#pragma unroll
      for (int r = 0; r < 4; ++r) os[ri * 16 + lr + r] = accs[ri][r];
  }
}

// kvB[bh][col][k]: col<64 -> sum_sp kvp[sp][bh][k][col]; col==64 -> sum_sp ksp;
// 65..79 -> 0 (bf16)
__global__ void build_kvB(const float* __restrict__ kvp, const float* __restrict__ ksp,
                          bf16_t* __restrict__ kvB) {
  int i = blockIdx.x * 256 + threadIdx.x;
  if (i >= 32 * 80 * 64) return;
  int k = i & 63;
  int col = (i >> 6) % 80;
  int bh = i / (80 * 64);
  float v = 0.f;
  if (col < 64) {
#pragma unroll
    for (int sp = 0; sp < 16; ++sp)
      v += kvp[((size_t)sp * 32 + bh) * 4096 + k * 64 + col];
  } else if (col == 64) {
#pragma unroll
    for (int sp = 0; sp < 16; ++sp)
      v += ksp[((size_t)sp * 32 + bh) * 64 + k];
  }
  kvB[i] = (bf16_t)v;
}

// ---------------------------------------------------------------------------
// attn[row, h*64+e] = (sum_d Q[row,h*64+d]*kv[d][e]) / max(denom,1e-6) + Q[row,h*64+e]
// denom comes free: kvB col 64 = ksum -> acc col 64 = q . ksum
// ---------------------------------------------------------------------------
__launch_bounds__(256, 2)
__global__ void attn_k(const bf16_t* __restrict__ Q, const bf16_t* __restrict__ kvB,
                       bf16_t* __restrict__ attn) {
  __shared__ __align__(16) bf16_t As[128 * 64];
  const int rt = blockIdx.x;     // 0..255 global row tile (never crosses b)
  const int h = blockIdx.y;      // 0..7
  const int b = rt >> 6;
  const int bh = b * 8 + h;
  const int tid = threadIdx.x, lane = tid & 63, wid = tid >> 6;
  const int srow = wid * 8 + (lane >> 3);
  const int scol = (lane & 7) * 8;
#pragma unroll
  for (int i = 0; i < 4; ++i)
    gll16(Q + (size_t)(rt * 128 + srow + i * 32) * 512 + h * 64 + scol, As + wid * 512 + i * 2048);

  f32x4 zero = {0.f, 0.f, 0.f, 0.f};
  f32x4 acc[2][5];
#pragma unroll
  for (int i = 0; i < 2; ++i)
#pragma unroll
    for (int j = 0; j < 5; ++j) acc[i][j] = zero;
  __syncthreads();

  const bf16_t* Bb = kvB + (size_t)bh * (80 * 64);
#pragma unroll
  for (int kk = 0; kk < 64; kk += 32) {
    bf16x8 af[2];
#pragma unroll
    for (int ri = 0; ri < 2; ++ri)
      af[ri] = *(const bf16x8*)&As[(wid * 32 + ri * 16 + (lane & 15)) * 64 + kk + (lane >> 4) * 8];
#pragma unroll
    for (int ci = 0; ci < 5; ++ci) {
      bf16x8 bfr = *(const bf16x8*)&Bb[(ci * 16 + (lane & 15)) * 64 + kk + (lane >> 4) * 8];
#pragma unroll
      for (int ri = 0; ri < 2; ++ri)
        acc[ri][ci] = __builtin_amdgcn_mfma_f32_16x16x32_bf16(af[ri], bfr, acc[ri][ci], 0, 0, 0);
    }
  }

  const int lr = (lane >> 4) * 4, lc = lane & 15;
#pragma unroll
  for (int ri = 0; ri < 2; ++ri)
#pragma unroll
    for (int r = 0; r < 4; ++r) {
      float dn = __shfl(acc[ri][4][r], lane & 48);  // col 64 lives at lane&15==0
      dn = fmaxf(dn, 1e-6f);
      float rinv = 1.0f / dn;
      int rl = wid * 32 + ri * 16 + lr + r;
#pragma unroll
      for (int ci = 0; ci < 4; ++ci) {
        int e = ci * 16 + lc;
        float qv = (float)As[rl * 64 + e];
        float o = acc[ri][ci][r] * rinv + qv;
        attn[(size_t)(rt * 128 + rl) * 512 + h * 64 + e] = (bf16_t)o;
      }
    }
}

// fused prep: cvt x (float4), cvt y (float4), transpose 4 weights to bf16
// flat grid: [0,4194304) x-cvt4 | [4194304,8388608) y-cvt4 | then 4x262144 wtrans
__global__ void prep_k(const float* __restrict__ x, const float* __restrict__ y,
                       const float* __restrict__ Wq, const float* __restrict__ Wk,
                       const float* __restrict__ Wv, const float* __restrict__ Wp,
                       bf16_t* __restrict__ xbf, bf16_t* __restrict__ ybf,
                       bf16_t* __restrict__ WqT, bf16_t* __restrict__ WkT,
                       bf16_t* __restrict__ WvT, bf16_t* __restrict__ WpT) {
  int i = blockIdx.x * 256 + threadIdx.x;
  if (i < 8388608) {
    const float* src = (i < 4194304) ? x : y;
    bf16_t* dst = (i < 4194304) ? xbf : ybf;
    int j = (i < 4194304) ? i : i - 4194304;
    float4 v = ((const float4*)src)[j];
    bf16x4 o;
    o[0] = (bf16_t)v.x;
    o[1] = (bf16_t)v.y;
    o[2] = (bf16_t)v.z;
    o[3] = (bf16_t)v.w;
    ((bf16x4*)dst)[j] = o;
  } else {
    int i2 = i - 8388608;
    int w = i2 >> 18, j = i2 & 262143;
    int n = j >> 9, k = j & 511;
    const float* W = (w == 0) ? Wq : (w == 1) ? Wk : (w == 2) ? Wv : Wp;
    bf16_t* WT = (w == 0) ? WqT : (w == 1) ? WkT : (w == 2) ? WvT : WpT;
    WT[j] = (bf16_t)W[k * 512 + n];
  }
}

extern "C" void kernel_launch(void* const* d_in, const int* in_sizes, int n_in,
                              void* d_out, int out_size, void* d_ws, size_t ws_size,
                              hipStream_t stream) {
  (void)in_sizes; (void)n_in; (void)out_size; (void)ws_size;
  const float* x  = (const float*)d_in[0];
  const float* y  = (const float*)d_in[1];
  const float* Wq = (const float*)d_in[2];
  const float* bq = (const float*)d_in[3];
  const float* Wk = (const float*)d_in[4];
  const float* bk = (const float*)d_in[5];
  const float* Wv = (const float*)d_in[6];
  const float* bv = (const float*)d_in[7];
  const float* Wp = (const float*)d_in[8];
  const float* bp = (const float*)d_in[9];
  float* out = (float*)d_out;

  char* ws = (char*)d_ws;
  const size_t MB = 1024 * 1024;
  bf16_t* xbf = (bf16_t*)(ws + 0);          // 32 MB
  bf16_t* ybf = (bf16_t*)(ws + 32 * MB);    // 32 MB
  bf16_t* Qb  = (bf16_t*)(ws + 64 * MB);    // 32 MB
  bf16_t* Kt  = (bf16_t*)(ws + 96 * MB);    // 32 MB (head-transposed)
  bf16_t* Vt  = (bf16_t*)(ws + 128 * MB);   // 32 MB (head-transposed)
  bf16_t* WqT = (bf16_t*)(ws + 160 * MB);   // 4 x 512 KB
  bf16_t* WkT = WqT + 512 * 512;
  bf16_t* WvT = WkT + 512 * 512;
  bf16_t* WpT = WvT + 512 * 512;
  float* kvp  = (float*)(ws + 163 * MB);    // 16*32*4096*4B = 8 MB
  float* ksp  = (float*)(ws + 171 * MB);    // 16*32*64*4B = 128 KB
  bf16_t* kvB = (bf16_t*)(ws + 172 * MB);   // 320 KB
  bf16_t* attn = xbf;                       // reuse (dead after Q gemm)

  // 0) fused prep: cvt x,y + transpose 4 weights
  prep_k<<<36864, 256, 0, stream>>>(x, y, Wq, Wk, Wv, Wp, xbf, ybf, WqT, WkT, WvT, WpT);

  // 1) fused Q/K/V projections (bias + softmax for Q,K; K,V head-transposed)
  qkv_k<<<dim3(256, 4, 3), 256, 0, stream>>>(xbf, ybf, WqT, WkT, WvT, bq, bk, bv, Qb, Kt, Vt);

  // 2) kv + ksum split-m partials (MFMA GEMM over m), then reduce+pack
  kv2_k<<<512, 256, 0, stream>>>(Kt, Vt, kvp, ksp);
  build_kvB<<<(32 * 80 * 64) / 256, 256, 0, stream>>>(kvp, ksp, kvB);

  // 3) q @ kv / denom + q
  attn_k<<<dim3(256, 8), 256, 0, stream>>>(Qb, kvB, attn);

  // 4) output projection -> fp32
  pgemm_k<<<dim3(256, 4), 256, 0, stream>>>(attn, WpT, bp, out);
}

// Round 4
// 345.465 us; speedup vs baseline: 1.1962x; 1.1962x over previous
//
#include <hip/hip_runtime.h>

typedef __bf16 bf16_t;
typedef __bf16 bf16x4 __attribute__((ext_vector_type(4)));
typedef __bf16 bf16x8 __attribute__((ext_vector_type(8)));
typedef float f32x4 __attribute__((ext_vector_type(4)));

#define AS1 __attribute__((address_space(1)))
#define AS3 __attribute__((address_space(3)))

// async global->LDS, 16B per lane; LDS dest = wave-uniform base + lane*16
__device__ __forceinline__ void gll16(const void* g, void* l) {
  __builtin_amdgcn_global_load_lds((AS1 void*)g, (AS3 void*)l, 16, 0, 0);
}

// ---------------------------------------------------------------------------
// GEMM core: C(32768x512) = act(A(32768x512,bf16) @ BT^T + bias)
// BT is W^T (512x512, bf16) so B-fragments read contiguous k.
// ACT: 0 = identity->bf16, 1 = per-64-group softmax->bf16, 2 = identity->fp32
// TRANS: store as T[(b*8+h)*64 + d][m] (head-transposed, for kv GEMM operands)
// LDS is passed IN (single allocation per kernel, even when called from a
// multi-branch kernel — 3 static copies cost 96 KB and 1 block/CU in R3).
// ---------------------------------------------------------------------------
__device__ __forceinline__ void gemm_core(const bf16_t* __restrict__ A,
                                          const bf16_t* __restrict__ BT,
                                          const float* __restrict__ bias,
                                          void* __restrict__ Cout,
                                          int rowbase, int colbase,
                                          int ACT, bool TRANS,
                                          bf16_t* As, bf16_t* Bs) {
  const int tid = threadIdx.x;
  const int lane = tid & 63, wid = tid >> 6;
  const int wr = wid >> 1, wc = wid & 1;

  f32x4 zero = {0.f, 0.f, 0.f, 0.f};
  f32x4 acc[4][4];
#pragma unroll
  for (int i = 0; i < 4; ++i)
#pragma unroll
    for (int j = 0; j < 4; ++j) acc[i][j] = zero;

  const int srow = wid * 8 + (lane >> 3);   // + i*32
  const int scol = (lane & 7) * 8;
  const size_t abase = (size_t)(rowbase + srow) * 512 + scol;
  const size_t bbase = (size_t)(colbase + srow) * 512 + scol;
  bf16_t* lA = As + wid * 512;
  bf16_t* lB = Bs + wid * 512;

  for (int k0 = 0; k0 < 512; k0 += 64) {
#pragma unroll
    for (int i = 0; i < 4; ++i) {
      gll16(A + abase + (size_t)i * (32 * 512) + k0, lA + i * 2048);
      gll16(BT + bbase + (size_t)i * (32 * 512) + k0, lB + i * 2048);
    }
    __syncthreads();
#pragma unroll
    for (int kk = 0; kk < 64; kk += 32) {
      bf16x8 af[4], bfr[4];
#pragma unroll
      for (int ri = 0; ri < 4; ++ri)
        af[ri] = *(const bf16x8*)&As[(wr * 64 + ri * 16 + (lane & 15)) * 64 + kk + (lane >> 4) * 8];
#pragma unroll
      for (int ci = 0; ci < 4; ++ci)
        bfr[ci] = *(const bf16x8*)&Bs[(wc * 64 + ci * 16 + (lane & 15)) * 64 + kk + (lane >> 4) * 8];
#pragma unroll
      for (int ri = 0; ri < 4; ++ri)
#pragma unroll
        for (int ci = 0; ci < 4; ++ci)
          acc[ri][ci] = __builtin_amdgcn_mfma_f32_16x16x32_bf16(af[ri], bfr[ci], acc[ri][ci], 0, 0, 0);
    }
    __syncthreads();
  }

  // epilogue: bias (+ softmax per 64-col head group)
  float bb[4];
#pragma unroll
  for (int ci = 0; ci < 4; ++ci) bb[ci] = bias[colbase + wc * 64 + ci * 16 + (lane & 15)];
#pragma unroll
  for (int ri = 0; ri < 4; ++ri)
#pragma unroll
    for (int ci = 0; ci < 4; ++ci)
#pragma unroll
      for (int r = 0; r < 4; ++r) acc[ri][ci][r] += bb[ci];

  if (ACT == 1) {
    // wave's 64 cols == one head group (col tile offsets are multiples of 64)
#pragma unroll
    for (int ri = 0; ri < 4; ++ri) {
#pragma unroll
      for (int r = 0; r < 4; ++r) {
        float m = fmaxf(fmaxf(acc[ri][0][r], acc[ri][1][r]), fmaxf(acc[ri][2][r], acc[ri][3][r]));
        m = fmaxf(m, __shfl_xor(m, 1));
        m = fmaxf(m, __shfl_xor(m, 2));
        m = fmaxf(m, __shfl_xor(m, 4));
        m = fmaxf(m, __shfl_xor(m, 8));
        float s = 0.f;
#pragma unroll
        for (int ci = 0; ci < 4; ++ci) {
          float p = __expf(acc[ri][ci][r] - m);
          acc[ri][ci][r] = p;
          s += p;
        }
        s += __shfl_xor(s, 1);
        s += __shfl_xor(s, 2);
        s += __shfl_xor(s, 4);
        s += __shfl_xor(s, 8);
        float rcp = 1.0f / s;
#pragma unroll
        for (int ci = 0; ci < 4; ++ci) acc[ri][ci][r] *= rcp;
      }
    }
  }

  const int lr = (lane >> 4) * 4, lc = lane & 15;
  if (TRANS) {
    // packed 8B stores: the 4 r-values are 4 consecutive m in T layout
#pragma unroll
    for (int ri = 0; ri < 4; ++ri)
#pragma unroll
      for (int ci = 0; ci < 4; ++ci) {
        bf16x4 pk;
#pragma unroll
        for (int r = 0; r < 4; ++r) pk[r] = (bf16_t)acc[ri][ci][r];
        int gm0 = rowbase + wr * 64 + ri * 16 + lr;
        int c = colbase + wc * 64 + ci * 16 + lc;
        size_t idx = ((size_t)((gm0 >> 13) * 8 + (c >> 6)) * 64 + (c & 63)) * 8192 + (gm0 & 8191);
        *(bf16x4*)&((bf16_t*)Cout)[idx] = pk;
      }
  } else {
#pragma unroll
    for (int ri = 0; ri < 4; ++ri)
#pragma unroll
      for (int ci = 0; ci < 4; ++ci)
#pragma unroll
        for (int r = 0; r < 4; ++r) {
          int gm = rowbase + wr * 64 + ri * 16 + lr + r;
          int c = colbase + wc * 64 + ci * 16 + lc;
          size_t idx = (size_t)gm * 512 + c;
          if (ACT == 2)
            ((float*)Cout)[idx] = acc[ri][ci][r];
          else
            ((bf16_t*)Cout)[idx] = (bf16_t)acc[ri][ci][r];
        }
  }
}

// fused Q/K/V projections: blockIdx.z selects which GEMM; ONE LDS allocation
__launch_bounds__(256, 2)
__global__ void qkv_k(const bf16_t* __restrict__ xbf, const bf16_t* __restrict__ ybf,
                      const bf16_t* __restrict__ WqT, const bf16_t* __restrict__ WkT,
                      const bf16_t* __restrict__ WvT,
                      const float* __restrict__ bq, const float* __restrict__ bk,
                      const float* __restrict__ bv,
                      bf16_t* __restrict__ Qb, bf16_t* __restrict__ Kt,
                      bf16_t* __restrict__ Vt) {
  __shared__ __align__(16) bf16_t As[128 * 64];
  __shared__ __align__(16) bf16_t Bs[128 * 64];
  const int rowbase = blockIdx.x * 128, colbase = blockIdx.y * 128;
  const int z = blockIdx.z;
  const bf16_t* A  = (z == 0) ? xbf : ybf;
  const bf16_t* BT = (z == 0) ? WqT : (z == 1) ? WkT : WvT;
  const float* bias = (z == 0) ? bq : (z == 1) ? bk : bv;
  void* C = (z == 0) ? (void*)Qb : (z == 1) ? (void*)Kt : (void*)Vt;
  int ACT = (z == 2) ? 0 : 1;
  bool TRANS = (z != 0);
  gemm_core(A, BT, bias, C, rowbase, colbase, ACT, TRANS, As, Bs);
}

// output projection -> fp32
__launch_bounds__(256, 2)
__global__ void pgemm_k(const bf16_t* __restrict__ A, const bf16_t* __restrict__ BT,
                        const float* __restrict__ bias, float* __restrict__ Cout) {
  __shared__ __align__(16) bf16_t As[128 * 64];
  __shared__ __align__(16) bf16_t Bs[128 * 64];
  gemm_core(A, BT, bias, Cout, blockIdx.x * 128, blockIdx.y * 128, 2, false, As, Bs);
}

// ---------------------------------------------------------------------------
// kv partials: kvp[sp][bh][d][e] = sum_{m in split sp} Kt[bh][d][m]*Vt[bh][e][m]
// ksp[sp][bh][d] likewise vs all-ones. No atomics; build_kvB reduces.
// ---------------------------------------------------------------------------
__launch_bounds__(256, 2)
__global__ void kv2_k(const bf16_t* __restrict__ Kt, const bf16_t* __restrict__ Vt,
                      float* __restrict__ kvp, float* __restrict__ ksp) {
  __shared__ __align__(16) bf16_t Ks[64 * 64];
  __shared__ __align__(16) bf16_t Vs[64 * 64];
  const int bh = blockIdx.x >> 4, sp = blockIdx.x & 15;
  const int tid = threadIdx.x, lane = tid & 63, wid = tid >> 6;
  const size_t base = (size_t)bh * 64 * 8192;
  const int m0 = sp * 512;
  const int srow = wid * 8 + (lane >> 3);  // + i*32
  const int scol = (lane & 7) * 8;

  f32x4 zero = {0.f, 0.f, 0.f, 0.f};
  f32x4 acc[4], accs[4];
#pragma unroll
  for (int i = 0; i < 4; ++i) { acc[i] = zero; accs[i] = zero; }
  bf16x8 ones;
#pragma unroll
  for (int j = 0; j < 8; ++j) ones[j] = (bf16_t)1.0f;

  for (int c = 0; c < 8; ++c) {
    const int mc = m0 + c * 64;
#pragma unroll
    for (int i = 0; i < 2; ++i) {
      size_t g = base + (size_t)(srow + i * 32) * 8192 + mc + scol;
      gll16(Kt + g, Ks + wid * 512 + i * 2048);
      gll16(Vt + g, Vs + wid * 512 + i * 2048);
    }
    __syncthreads();
#pragma unroll
    for (int kk = 0; kk < 64; kk += 32) {
      bf16x8 af[4];
#pragma unroll
      for (int ri = 0; ri < 4; ++ri)
        af[ri] = *(const bf16x8*)&Ks[(ri * 16 + (lane & 15)) * 64 + kk + (lane >> 4) * 8];
      bf16x8 bfr = *(const bf16x8*)&Vs[(wid * 16 + (lane & 15)) * 64 + kk + (lane >> 4) * 8];
#pragma unroll
      for (int ri = 0; ri < 4; ++ri)
        acc[ri] = __builtin_amdgcn_mfma_f32_16x16x32_bf16(af[ri], bfr, acc[ri], 0, 0, 0);
      if (wid == 0) {
#pragma unroll
        for (int ri = 0; ri < 4; ++ri)
          accs[ri] = __builtin_amdgcn_mfma_f32_16x16x32_bf16(af[ri], ones, accs[ri], 0, 0, 0);
      }
    }
    __syncthreads();
  }

  const int lr = (lane >> 4) * 4, lc = lane & 15;
  float* o = kvp + ((size_t)sp * 32 + bh) * 4096;
#pragma unroll
  for (int ri = 0; ri < 4; ++ri)
#pragma unroll
    for (int r = 0; r < 4; ++r)
      o[(ri * 16 + lr + r) * 64 + wid * 16 + lc] = acc[ri][r];
  if (wid == 0 && lc == 0) {
    float* os = ksp + ((size_t)sp * 32 + bh) * 64;
#pragma unroll
    for (int ri = 0; ri < 4; ++ri)
#pragma unroll
      for (int r = 0; r < 4; ++r) os[ri * 16 + lr + r] = accs[ri][r];
  }
}

// kvB[bh][col][k]: col<64 -> sum_sp kvp[sp][bh][k][col]; col==64 -> sum_sp ksp;
// 65..79 -> 0 (bf16)
__global__ void build_kvB(const float* __restrict__ kvp, const float* __restrict__ ksp,
                          bf16_t* __restrict__ kvB) {
  int i = blockIdx.x * 256 + threadIdx.x;
  if (i >= 32 * 80 * 64) return;
  int k = i & 63;
  int col = (i >> 6) % 80;
  int bh = i / (80 * 64);
  float v = 0.f;
  if (col < 64) {
#pragma unroll
    for (int sp = 0; sp < 16; ++sp)
      v += kvp[((size_t)sp * 32 + bh) * 4096 + k * 64 + col];
  } else if (col == 64) {
#pragma unroll
    for (int sp = 0; sp < 16; ++sp)
      v += ksp[((size_t)sp * 32 + bh) * 64 + k];
  }
  kvB[i] = (bf16_t)v;
}

// ---------------------------------------------------------------------------
// attn[row, h*64+e] = (sum_d Q[row,h*64+d]*kv[d][e]) / max(denom,1e-6) + Q[row,h*64+e]
// denom comes free: kvB col 64 = ksum -> acc col 64 = q . ksum
// ---------------------------------------------------------------------------
__launch_bounds__(256, 2)
__global__ void attn_k(const bf16_t* __restrict__ Q, const bf16_t* __restrict__ kvB,
                       bf16_t* __restrict__ attn) {
  __shared__ __align__(16) bf16_t As[128 * 64];
  const int rt = blockIdx.x;     // 0..255 global row tile (never crosses b)
  const int h = blockIdx.y;      // 0..7
  const int b = rt >> 6;
  const int bh = b * 8 + h;
  const int tid = threadIdx.x, lane = tid & 63, wid = tid >> 6;
  const int srow = wid * 8 + (lane >> 3);
  const int scol = (lane & 7) * 8;
#pragma unroll
  for (int i = 0; i < 4; ++i)
    gll16(Q + (size_t)(rt * 128 + srow + i * 32) * 512 + h * 64 + scol, As + wid * 512 + i * 2048);

  f32x4 zero = {0.f, 0.f, 0.f, 0.f};
  f32x4 acc[2][5];
#pragma unroll
  for (int i = 0; i < 2; ++i)
#pragma unroll
    for (int j = 0; j < 5; ++j) acc[i][j] = zero;
  __syncthreads();

  const bf16_t* Bb = kvB + (size_t)bh * (80 * 64);
#pragma unroll
  for (int kk = 0; kk < 64; kk += 32) {
    bf16x8 af[2];
#pragma unroll
    for (int ri = 0; ri < 2; ++ri)
      af[ri] = *(const bf16x8*)&As[(wid * 32 + ri * 16 + (lane & 15)) * 64 + kk + (lane >> 4) * 8];
#pragma unroll
    for (int ci = 0; ci < 5; ++ci) {
      bf16x8 bfr = *(const bf16x8*)&Bb[(ci * 16 + (lane & 15)) * 64 + kk + (lane >> 4) * 8];
#pragma unroll
      for (int ri = 0; ri < 2; ++ri)
        acc[ri][ci] = __builtin_amdgcn_mfma_f32_16x16x32_bf16(af[ri], bfr, acc[ri][ci], 0, 0, 0);
    }
  }

  const int lr = (lane >> 4) * 4, lc = lane & 15;
#pragma unroll
  for (int ri = 0; ri < 2; ++ri)
#pragma unroll
    for (int r = 0; r < 4; ++r) {
      float dn = __shfl(acc[ri][4][r], lane & 48);  // col 64 lives at lane&15==0
      dn = fmaxf(dn, 1e-6f);
      float rinv = 1.0f / dn;
      int rl = wid * 32 + ri * 16 + lr + r;
#pragma unroll
      for (int ci = 0; ci < 4; ++ci) {
        int e = ci * 16 + lc;
        float qv = (float)As[rl * 64 + e];
        float o = acc[ri][ci][r] * rinv + qv;
        attn[(size_t)(rt * 128 + rl) * 512 + h * 64 + e] = (bf16_t)o;
      }
    }
}

// fused prep: cvt x (float4), cvt y (float4), transpose 4 weights to bf16
__global__ void prep_k(const float* __restrict__ x, const float* __restrict__ y,
                       const float* __restrict__ Wq, const float* __restrict__ Wk,
                       const float* __restrict__ Wv, const float* __restrict__ Wp,
                       bf16_t* __restrict__ xbf, bf16_t* __restrict__ ybf,
                       bf16_t* __restrict__ WqT, bf16_t* __restrict__ WkT,
                       bf16_t* __restrict__ WvT, bf16_t* __restrict__ WpT) {
  int i = blockIdx.x * 256 + threadIdx.x;
  if (i < 8388608) {
    const float* src = (i < 4194304) ? x : y;
    bf16_t* dst = (i < 4194304) ? xbf : ybf;
    int j = (i < 4194304) ? i : i - 4194304;
    float4 v = ((const float4*)src)[j];
    bf16x4 o;
    o[0] = (bf16_t)v.x;
    o[1] = (bf16_t)v.y;
    o[2] = (bf16_t)v.z;
    o[3] = (bf16_t)v.w;
    ((bf16x4*)dst)[j] = o;
  } else {
    int i2 = i - 8388608;
    int w = i2 >> 18, j = i2 & 262143;
    int n = j >> 9, k = j & 511;
    const float* W = (w == 0) ? Wq : (w == 1) ? Wk : (w == 2) ? Wv : Wp;
    bf16_t* WT = (w == 0) ? WqT : (w == 1) ? WkT : (w == 2) ? WvT : WpT;
    WT[j] = (bf16_t)W[k * 512 + n];
  }
}

extern "C" void kernel_launch(void* const* d_in, const int* in_sizes, int n_in,
                              void* d_out, int out_size, void* d_ws, size_t ws_size,
                              hipStream_t stream) {
  (void)in_sizes; (void)n_in; (void)out_size; (void)ws_size;
  const float* x  = (const float*)d_in[0];
  const float* y  = (const float*)d_in[1];
  const float* Wq = (const float*)d_in[2];
  const float* bq = (const float*)d_in[3];
  const float* Wk = (const float*)d_in[4];
  const float* bk = (const float*)d_in[5];
  const float* Wv = (const float*)d_in[6];
  const float* bv = (const float*)d_in[7];
  const float* Wp = (const float*)d_in[8];
  const float* bp = (const float*)d_in[9];
  float* out = (float*)d_out;

  char* ws = (char*)d_ws;
  const size_t MB = 1024 * 1024;
  bf16_t* xbf = (bf16_t*)(ws + 0);          // 32 MB
  bf16_t* ybf = (bf16_t*)(ws + 32 * MB);    // 32 MB
  bf16_t* Qb  = (bf16_t*)(ws + 64 * MB);    // 32 MB
  bf16_t* Kt  = (bf16_t*)(ws + 96 * MB);    // 32 MB (head-transposed)
  bf16_t* Vt  = (bf16_t*)(ws + 128 * MB);   // 32 MB (head-transposed)
  bf16_t* WqT = (bf16_t*)(ws + 160 * MB);   // 4 x 512 KB
  bf16_t* WkT = WqT + 512 * 512;
  bf16_t* WvT = WkT + 512 * 512;
  bf16_t* WpT = WvT + 512 * 512;
  float* kvp  = (float*)(ws + 163 * MB);    // 16*32*4096*4B = 8 MB
  float* ksp  = (float*)(ws + 171 * MB);    // 16*32*64*4B = 128 KB
  bf16_t* kvB = (bf16_t*)(ws + 172 * MB);   // 320 KB
  bf16_t* attn = xbf;                       // reuse (dead after Q gemm)

  // 0) fused prep: cvt x,y + transpose 4 weights
  prep_k<<<36864, 256, 0, stream>>>(x, y, Wq, Wk, Wv, Wp, xbf, ybf, WqT, WkT, WvT, WpT);

  // 1) fused Q/K/V projections (bias + softmax for Q,K; K,V head-transposed)
  qkv_k<<<dim3(256, 4, 3), 256, 0, stream>>>(xbf, ybf, WqT, WkT, WvT, bq, bk, bv, Qb, Kt, Vt);

  // 2) kv + ksum split-m partials (MFMA GEMM over m), then reduce+pack
  kv2_k<<<512, 256, 0, stream>>>(Kt, Vt, kvp, ksp);
  build_kvB<<<(32 * 80 * 64) / 256, 256, 0, stream>>>(kvp, ksp, kvB);

  // 3) q @ kv / denom + q
  attn_k<<<dim3(256, 8), 256, 0, stream>>>(Qb, kvB, attn);

  // 4) output projection -> fp32
  pgemm_k<<<dim3(256, 4), 256, 0, stream>>>(attn, WpT, bp, out);
}